// Round 3
// baseline (699.836 us; speedup 1.0000x reference)
//
#include <hip/hip_runtime.h>

// AttentionBasedNN: 4-layer additive (Bahdanau) attention + residual FCs + head.
// VEC=1280, HID=128, B=4, S=256. fp32 (no fp32 MFMA on CDNA4 -> vector ALU).
//
// Round-3: (a) gemm_k gets register double-buffering (prefetch next tile
// during compute) and QK split-K=8 -> grid 512 (2 blocks/CU); (b) scores+
// softmax+PV+residual+LN+FC1 fused into mega_k (256 blocks, 4 rows each);
// (c) latency-bound tail4_k split into parallel pieces. 13 dispatches.

#define DEV __device__ __forceinline__

static constexpr int VEC = 1280;
static constexpr int HID = 128;
static constexpr int BB  = 4;
static constexpr int SS  = 256;
static constexpr int MROWS = BB * SS;   // 1024
static constexpr int NPART = 8;         // QK split-K partials

DEV float ftanh(float x) {
  float e = __expf(2.0f * x);
  return 1.0f - __fdividef(2.0f, e + 1.0f);
}

DEV float waveSum(float v) {
#pragma unroll
  for (int off = 32; off > 0; off >>= 1) v += __shfl_xor(v, off, 64);
  return v;
}
DEV float waveMax(float v) {
#pragma unroll
  for (int off = 32; off > 0; off >>= 1) v = fmaxf(v, __shfl_xor(v, off, 64));
  return v;
}
// blockDim.x == 256 (4 waves) everywhere these are used.
DEV float blockSum(float v, float* red) {
  v = waveSum(v);
  int tid = threadIdx.x;
  if ((tid & 63) == 0) red[tid >> 6] = v;
  __syncthreads();
  float r = (red[0] + red[1]) + (red[2] + red[3]);
  __syncthreads();
  return r;
}
DEV float blockMax(float v, float* red) {
  v = waveMax(v);
  int tid = threadIdx.x;
  if ((tid & 63) == 0) red[tid >> 6] = v;
  __syncthreads();
  float r = fmaxf(fmaxf(red[0], red[1]), fmaxf(red[2], red[3]));
  __syncthreads();
  return r;
}

// ---------------------------------------------------------------------------
// fp32 GEMM, 64x64 tile, BK=16, 256 threads, 4x4 microtile, register
// double-buffered staging (prefetch tile k+1 while computing tile k).
// MODE==0: full-K, z=1; epilogue bias/residual.
// MODE==1: blockIdx.z = K-split slice (kChunk each); C offset z*sCb into a
//          disjoint partial buffer (plain store; consumer sums partials).
// Dual-B: output col n < nSplitB reads B0, else B1 at col n-nSplitB (same ldB).
// ---------------------------------------------------------------------------
template <int MODE, bool OBIAS, bool ORES>
__global__ __launch_bounds__(256) void gemm_k(
    const float* __restrict__ A,
    const float* __restrict__ B0, const float* __restrict__ B1, int nSplitB,
    int ldB,
    float* __restrict__ C, long sCb,
    const float* __restrict__ oBias, const float* __restrict__ res,
    int N, int K, int kChunk) {
  const int n0 = blockIdx.x * 64;
  const int m0 = blockIdx.y * 64;
  const int z  = blockIdx.z;

  float* Cb = C + (MODE == 1 ? (long)z * sCb : 0L);
  const float* Bsel;
  int nb;
  if (n0 < nSplitB) { Bsel = B0; nb = n0; } else { Bsel = B1; nb = n0 - nSplitB; }

  const int kBeg = (MODE == 1) ? z * kChunk : 0;
  const int kEnd = (MODE == 1) ? kBeg + kChunk : K;

  __shared__ float As[16][68];  // [k][m]
  __shared__ float Bs[16][68];  // [k][n]

  const int tid = threadIdx.x;
  const int tx = tid & 15, ty = tid >> 4;
  const int ar = tid >> 2, ac = (tid & 3) << 2;   // A: row 0..63, k-col {0,4,8,12}
  const int br = tid >> 4, bc = (tid & 15) << 2;  // B: k-row 0..15, col 0..60

  float acc[4][4] = {};

  // prefetch first tile
  float4 a4 = *(const float4*)(A + (size_t)(m0 + ar) * K + kBeg + ac);
  float4 b4 = *(const float4*)(Bsel + (size_t)(kBeg + br) * ldB + nb + bc);

  for (int kt = kBeg; kt < kEnd; kt += 16) {
    __syncthreads();  // previous compute done before overwriting LDS
    As[ac + 0][ar] = a4.x;
    As[ac + 1][ar] = a4.y;
    As[ac + 2][ar] = a4.z;
    As[ac + 3][ar] = a4.w;
    *(float4*)&Bs[br][bc] = b4;
    __syncthreads();
    if (kt + 16 < kEnd) {  // issue next-tile loads; latency hides under compute
      a4 = *(const float4*)(A + (size_t)(m0 + ar) * K + (kt + 16) + ac);
      b4 = *(const float4*)(Bsel + (size_t)(kt + 16 + br) * ldB + nb + bc);
    }
#pragma unroll
    for (int kk = 0; kk < 16; ++kk) {
      const float4 av = *(const float4*)&As[kk][ty << 2];
      const float4 bv = *(const float4*)&Bs[kk][tx << 2];
      const float a[4] = {av.x, av.y, av.z, av.w};
      const float b[4] = {bv.x, bv.y, bv.z, bv.w};
#pragma unroll
      for (int i = 0; i < 4; ++i)
#pragma unroll
        for (int j = 0; j < 4; ++j) acc[i][j] = fmaf(a[i], b[j], acc[i][j]);
    }
  }

#pragma unroll
  for (int i = 0; i < 4; ++i) {
    const int m = m0 + (ty << 2) + i;
#pragma unroll
    for (int j = 0; j < 4; ++j) {
      const int n = n0 + (tx << 2) + j;
      float v = acc[i][j];
      if (OBIAS) v += oBias[n];
      if (ORES) v += res[(size_t)m * N + n];
      Cb[(size_t)m * N + n] = v;
    }
  }
}

// ---------------------------------------------------------------------------
// Mega-fused layer middle: scores + softmax + PV + residual + LN + FC1+ReLU.
// Grid (64, B): block = (i-tile of 4 query rows, b). 256 threads.
// QKp: NPART disjoint K-split partials of Xin@[Wq|Wk], layout [1024][256]
// (cols 0..127 = Q, 128..255 = K), partial stride ps.
// Outputs: Yb = LN(attn@Xin + Xin) rows; H = relu(Yb@rW1 + b1) rows.
// ---------------------------------------------------------------------------
__global__ __launch_bounds__(256) void mega_k(
    const float* __restrict__ QKp, long ps,
    const float* __restrict__ wv,
    const float* __restrict__ Xin,
    const float* __restrict__ rW1, const float* __restrict__ rb1,
    float* __restrict__ Yb, float* __restrict__ H) {
  const int b = blockIdx.y, i0 = blockIdx.x * 4, tid = threadIdx.x;
  __shared__ float qs[4][128], wvs[128];
  __shared__ float aw[4][256];
  __shared__ float red[4];
  __shared__ float Ys[4][1280];

  // q fragments for the 4 rows (sum of NPART partials)
  for (int idx = tid; idx < 512; idx += 256) {
    const int r = idx >> 7, h = idx & 127;
    const size_t off = ((size_t)(b * 256 + i0 + r)) * 256 + h;
    float v = 0.0f;
#pragma unroll
    for (int p = 0; p < NPART; ++p) v += QKp[(long)p * ps + off];
    qs[r][h] = v;
  }
  if (tid < 128) wvs[tid] = wv[tid];
  __syncthreads();

  // scores: thread j = tid over 256 keys, 4 query rows
  const size_t kb = ((size_t)(b * 256 + tid)) * 256 + 128;
  float s[4] = {0, 0, 0, 0};
  for (int h = 0; h < 128; h += 4) {
    float kx = 0, ky = 0, kz = 0, kw = 0;
#pragma unroll
    for (int p = 0; p < NPART; ++p) {
      const float4 t = *(const float4*)(QKp + (long)p * ps + kb + h);
      kx += t.x; ky += t.y; kz += t.z; kw += t.w;
    }
    const float w0 = wvs[h], w1 = wvs[h + 1], w2 = wvs[h + 2], w3 = wvs[h + 3];
#pragma unroll
    for (int r = 0; r < 4; ++r) {
      s[r] += w0 * ftanh(qs[r][h] + kx) + w1 * ftanh(qs[r][h + 1] + ky) +
              w2 * ftanh(qs[r][h + 2] + kz) + w3 * ftanh(qs[r][h + 3] + kw);
    }
  }
#pragma unroll
  for (int r = 0; r < 4; ++r) {
    const float mx = blockMax(s[r], red);
    const float e = __expf(s[r] - mx);
    const float tot = blockSum(e, red);
    aw[r][tid] = e / tot;
  }
  __syncthreads();

  // PV: each thread owns cols {tid, tid+256, ..., tid+1024} for all 4 rows
  float acc[4][5] = {};
  const float* Xb = Xin + (size_t)b * SS * VEC;
  for (int j = 0; j < 256; ++j) {
    const float a0 = aw[0][j], a1 = aw[1][j], a2 = aw[2][j], a3 = aw[3][j];
    const float* xr = Xb + (size_t)j * VEC + tid;
#pragma unroll
    for (int k = 0; k < 5; ++k) {
      const float xv = xr[k * 256];
      acc[0][k] = fmaf(a0, xv, acc[0][k]);
      acc[1][k] = fmaf(a1, xv, acc[1][k]);
      acc[2][k] = fmaf(a2, xv, acc[2][k]);
      acc[3][k] = fmaf(a3, xv, acc[3][k]);
    }
  }

  // residual + LN per row; keep normalized row in LDS for FC1, write Yb
#pragma unroll
  for (int r = 0; r < 4; ++r) {
    const float* xq = Xb + (size_t)(i0 + r) * VEC + tid;
    float sum = 0.0f;
#pragma unroll
    for (int k = 0; k < 5; ++k) {
      acc[r][k] += xq[k * 256];
      sum += acc[r][k];
    }
    sum = blockSum(sum, red);
    const float m = sum * (1.0f / VEC);
    float sq = 0.0f;
#pragma unroll
    for (int k = 0; k < 5; ++k) {
      const float dl = acc[r][k] - m;
      sq += dl * dl;
    }
    sq = blockSum(sq, red);
    const float rstd = rsqrtf(sq * (1.0f / VEC) + 1e-5f);
    float* yrow = Yb + ((size_t)(b * 256 + i0 + r)) * VEC;
#pragma unroll
    for (int k = 0; k < 5; ++k) {
      const float v = (acc[r][k] - m) * rstd;
      Ys[r][tid + k * 256] = v;
      yrow[tid + k * 256] = v;
    }
  }
  __syncthreads();

  // FC1: H[4 rows][128] = relu(Ys @ rW1 + b1). 64 threads/row, 2 cols/thread.
  {
    const int r = tid >> 6, h0 = (tid & 63) * 2;
    float f0 = 0.0f, f1 = 0.0f;
#pragma unroll 8
    for (int k = 0; k < 1280; ++k) {
      const float y = Ys[r][k];  // wave-uniform -> LDS broadcast
      const float2 w = *(const float2*)(rW1 + (size_t)k * HID + h0);
      f0 = fmaf(y, w.x, f0);
      f1 = fmaf(y, w.y, f1);
    }
    float* hrow = H + ((size_t)(b * 256 + i0 + r)) * HID;
    hrow[h0]     = fmaxf(f0 + rb1[h0], 0.0f);
    hrow[h0 + 1] = fmaxf(f1 + rb1[h0 + 1], 0.0f);
  }
}

// ---------------------------------------------------------------------------
// Layer-4 tail pieces.
// scores4_k: grid (B). q row taken from QKp partials at row (b*256+lp).
__global__ __launch_bounds__(256) void scores4_k(const float* __restrict__ QKp,
                                                 long ps,
                                                 const float* __restrict__ wv4,
                                                 const int* __restrict__ lys,
                                                 float* __restrict__ aw4) {
  const int b = blockIdx.x, tid = threadIdx.x;
  __shared__ float qs[128], wvs[128], red[4];
  const int lp = lys[0];
  if (tid < 128) {
    const size_t off = ((size_t)(b * 256 + lp)) * 256 + tid;
    float v = 0.0f;
#pragma unroll
    for (int p = 0; p < NPART; ++p) v += QKp[(long)p * ps + off];
    qs[tid] = v;
    wvs[tid] = wv4[tid];
  }
  __syncthreads();
  const size_t kb = ((size_t)(b * 256 + tid)) * 256 + 128;
  float s = 0.0f;
  for (int h = 0; h < 128; h += 4) {
    float kx = 0, ky = 0, kz = 0, kw = 0;
#pragma unroll
    for (int p = 0; p < NPART; ++p) {
      const float4 t = *(const float4*)(QKp + (long)p * ps + kb + h);
      kx += t.x; ky += t.y; kz += t.z; kw += t.w;
    }
    s += wvs[h + 0] * ftanh(qs[h + 0] + kx);
    s += wvs[h + 1] * ftanh(qs[h + 1] + ky);
    s += wvs[h + 2] * ftanh(qs[h + 2] + kz);
    s += wvs[h + 3] * ftanh(qs[h + 3] + kw);
  }
  const float mx = blockMax(s, red);
  const float e = __expf(s - mx);
  const float tot = blockSum(e, red);
  aw4[b * 256 + tid] = e / tot;
}

// pv4_k: grid (B, 5). A4[b][c] = sum_j aw4[b][j]*X3[b,j,c] + X3[b,lp,c].
__global__ __launch_bounds__(256) void pv4_k(const float* __restrict__ aw4,
                                             const float* __restrict__ X3,
                                             const int* __restrict__ lys,
                                             float* __restrict__ A4) {
  const int b = blockIdx.x, c = blockIdx.y * 256 + threadIdx.x;
  __shared__ float aws[256];
  aws[threadIdx.x] = aw4[b * 256 + threadIdx.x];
  __syncthreads();
  const float* Xb = X3 + (size_t)b * SS * VEC;
  float acc = 0.0f;
#pragma unroll 8
  for (int j = 0; j < 256; ++j) acc = fmaf(aws[j], Xb[(size_t)j * VEC + c], acc);
  acc += Xb[(size_t)lys[0] * VEC + c];
  A4[b * VEC + c] = acc;
}

// lnhead_k: grid (B). LN(A4[b]) then 1280->32(relu)->12(relu)->2 head.
__global__ __launch_bounds__(256) void lnhead_k(
    const float* __restrict__ A4,
    const float* __restrict__ hW1, const float* __restrict__ hb1,
    const float* __restrict__ hW2, const float* __restrict__ hb2,
    const float* __restrict__ hW3, const float* __restrict__ hb3,
    float* __restrict__ out) {
  const int b = blockIdx.x, tid = threadIdx.x;
  __shared__ float xrow[1280], partial[256], red[4];
  __shared__ float h1s[32], h2s[12];
  float v[5];
  float sum = 0.0f;
#pragma unroll
  for (int k = 0; k < 5; ++k) {
    v[k] = A4[b * VEC + tid + k * 256];
    sum += v[k];
  }
  sum = blockSum(sum, red);
  const float m = sum * (1.0f / VEC);
  float sq = 0.0f;
#pragma unroll
  for (int k = 0; k < 5; ++k) {
    const float dl = v[k] - m;
    sq += dl * dl;
  }
  sq = blockSum(sq, red);
  const float rstd = rsqrtf(sq * (1.0f / VEC) + 1e-5f);
#pragma unroll
  for (int k = 0; k < 5; ++k) xrow[tid + k * 256] = (v[k] - m) * rstd;
  __syncthreads();
  {
    const int n = tid & 31, sl = tid >> 5;
    float p = 0.0f;
    for (int k = sl * 160; k < sl * 160 + 160; ++k)
      p = fmaf(xrow[k], hW1[(size_t)k * 32 + n], p);
    partial[tid] = p;
  }
  __syncthreads();
  if (tid < 32) {
    float t = 0.0f;
#pragma unroll
    for (int s2 = 0; s2 < 8; ++s2) t += partial[s2 * 32 + tid];
    h1s[tid] = fmaxf(t + hb1[tid], 0.0f);
  }
  __syncthreads();
  if (tid < 12) {
    float t = 0.0f;
#pragma unroll
    for (int k = 0; k < 32; ++k) t = fmaf(h1s[k], hW2[k * 12 + tid], t);
    h2s[tid] = fmaxf(t + hb2[tid], 0.0f);
  }
  __syncthreads();
  if (tid < 2) {
    float t = 0.0f;
#pragma unroll
    for (int k = 0; k < 12; ++k) t = fmaf(h2s[k], hW3[k * 2 + tid], t);
    out[b * 2 + tid] = t + hb3[tid];
  }
}

// ---------------------------------------------------------------------------
extern "C" void kernel_launch(void* const* d_in, const int* in_sizes, int n_in,
                              void* d_out, int out_size, void* d_ws, size_t ws_size,
                              hipStream_t stream) {
  const float* X = (const float*)d_in[0];
  const int* lys = (const int*)d_in[1];
  const float* Wq[4] = {(const float*)d_in[2], (const float*)d_in[5],
                        (const float*)d_in[8], (const float*)d_in[11]};
  const float* Wk[4] = {(const float*)d_in[3], (const float*)d_in[6],
                        (const float*)d_in[9], (const float*)d_in[12]};
  const float* wv[4] = {(const float*)d_in[4], (const float*)d_in[7],
                        (const float*)d_in[10], (const float*)d_in[13]};
  const float* rW1[3] = {(const float*)d_in[14], (const float*)d_in[18],
                         (const float*)d_in[22]};
  const float* rb1[3] = {(const float*)d_in[15], (const float*)d_in[19],
                         (const float*)d_in[23]};
  const float* rW2[3] = {(const float*)d_in[16], (const float*)d_in[20],
                         (const float*)d_in[24]};
  const float* rb2[3] = {(const float*)d_in[17], (const float*)d_in[21],
                         (const float*)d_in[25]};
  const float* hW1 = (const float*)d_in[26];
  const float* hb1 = (const float*)d_in[27];
  const float* hW2 = (const float*)d_in[28];
  const float* hb2 = (const float*)d_in[29];
  const float* hW3 = (const float*)d_in[30];
  const float* hb3 = (const float*)d_in[31];
  float* out = (float*)d_out;

  // Workspace (floats), ~25 MB.
  float* ws = (float*)d_ws;
  const long QK_PS = 262144;                 // 1024*256 partial stride
  float* QKp  = ws;                          // NPART x 1 MB
  float* Yb   = QKp + (long)NPART * QK_PS;   // 1024*1280
  float* H    = Yb + 1310720;                // 1024*128
  float* buf0 = H + 131072;                  // 1024*1280
  float* buf1 = buf0 + 1310720;              // 1024*1280
  float* aw4  = buf1 + 1310720;              // 4*256
  float* A4   = aw4 + 1024;                  // 4*1280

  const int NSPLIT_NONE = 1 << 30;
  const float* P[3] = {X, buf0, buf1};
  float* Q[3] = {buf0, buf1, buf0};

  for (int l = 0; l < 3; ++l) {
    const float* Xin = P[l];
    // QKp[z] = Xin @ [Wq|Wk] over K-slice z (8 slices of 160). grid 512.
    gemm_k<1, false, false><<<dim3(4, 16, NPART), 256, 0, stream>>>(
        Xin, Wq[l], Wk[l], HID, HID, QKp, QK_PS, nullptr, nullptr,
        256, VEC, 160);
    // fused scores/softmax/PV/residual/LN/FC1
    mega_k<<<dim3(64, BB), 256, 0, stream>>>(QKp, QK_PS, wv[l], Xin, rW1[l],
                                             rb1[l], Yb, H);
    // Xout = H @ rW2 + b2 + Yb
    gemm_k<0, true, true><<<dim3(20, 16, 1), 256, 0, stream>>>(
        H, rW2[l], rW2[l], NSPLIT_NONE, VEC, Q[l], 0, rb2[l], Yb,
        VEC, HID, 0);
  }

  const float* X3 = Q[2];  // buf0
  // Layer 4: full QK projection (wasteful on Q side but 512-block parallel).
  gemm_k<1, false, false><<<dim3(4, 16, NPART), 256, 0, stream>>>(
      X3, Wq[3], Wk[3], HID, HID, QKp, QK_PS, nullptr, nullptr,
      256, VEC, 160);
  scores4_k<<<dim3(BB), 256, 0, stream>>>(QKp, QK_PS, wv[3], lys, aw4);
  pv4_k<<<dim3(BB, 5), 256, 0, stream>>>(aw4, X3, lys, A4);
  lnhead_k<<<dim3(BB), 256, 0, stream>>>(A4, hW1, hb1, hW2, hb2, hW3, hb3, out);
}

// Round 4
// 445.175 us; speedup vs baseline: 1.5720x; 1.5720x over previous
//
#include <hip/hip_runtime.h>

// AttentionBasedNN: 4-layer additive (Bahdanau) attention + residual FCs + head.
// VEC=1280, HID=128, B=4, S=256. fp32 (no fp32 MFMA on CDNA4 -> vector ALU).
//
// Round-4: de-fused into medium kernels with >=2 blocks/CU and coalesced
// access. QK partials reduced ONCE into dense Qd + transposed KT (scatter
// paid on the store side, once). Scores kernel reads KT coalesced.
// PV is a proper batched tiled GEMM. 26 dispatches.

#define DEV __device__ __forceinline__

static constexpr int VEC = 1280;
static constexpr int HID = 128;
static constexpr int BB  = 4;
static constexpr int SS  = 256;
static constexpr int MROWS = BB * SS;   // 1024
static constexpr int NPART = 8;         // split-K partials (QK and FC1)

DEV float ftanh(float x) {
  float e = __expf(2.0f * x);
  return 1.0f - __fdividef(2.0f, e + 1.0f);
}

DEV float waveSum(float v) {
#pragma unroll
  for (int off = 32; off > 0; off >>= 1) v += __shfl_xor(v, off, 64);
  return v;
}
DEV float waveMax(float v) {
#pragma unroll
  for (int off = 32; off > 0; off >>= 1) v = fmaxf(v, __shfl_xor(v, off, 64));
  return v;
}
// blockDim.x == 256 (4 waves) everywhere these are used.
DEV float blockSum(float v, float* red) {
  v = waveSum(v);
  int tid = threadIdx.x;
  if ((tid & 63) == 0) red[tid >> 6] = v;
  __syncthreads();
  float r = (red[0] + red[1]) + (red[2] + red[3]);
  __syncthreads();
  return r;
}
DEV float blockMax(float v, float* red) {
  v = waveMax(v);
  int tid = threadIdx.x;
  if ((tid & 63) == 0) red[tid >> 6] = v;
  __syncthreads();
  float r = fmaxf(fmaxf(red[0], red[1]), fmaxf(red[2], red[3]));
  __syncthreads();
  return r;
}

// ---------------------------------------------------------------------------
// fp32 GEMM, 64x64 tile, BK=16, 256 threads, 4x4 microtile, register
// double-buffered staging.
// MODE==0: plain (gridDim.z==1).
// MODE==1: blockIdx.z = K-split slice (kChunk each); C += z*sCb (disjoint
//          partial buffers; consumer sums).
// MODE==2: blockIdx.z = batch; A += z*sAb, B += z*sBb, C/res += z*sCb.
// AFUSE: A element = relu(sum of NPART partials (stride aPart) + aBias[k]).
// Dual-B: output col n < nSplitB reads B0, else B1 at col n-nSplitB (same ldB).
// ---------------------------------------------------------------------------
template <int MODE, bool AFUSE, bool OBIAS, bool ORES>
__global__ __launch_bounds__(256) void gemm_k(
    const float* __restrict__ A, long sAb, long aPart,
    const float* __restrict__ B0, const float* __restrict__ B1, int nSplitB,
    long sBb, int ldB,
    float* __restrict__ C, long sCb,
    const float* __restrict__ aBias, const float* __restrict__ oBias,
    const float* __restrict__ res,
    int N, int K, int kChunk) {
  const int n0 = blockIdx.x * 64;
  const int m0 = blockIdx.y * 64;
  const int z  = blockIdx.z;

  const float* Ab = A + (MODE == 2 ? (long)z * sAb : 0L);
  float*       Cb = C + (MODE >= 1 ? (long)z * sCb : 0L);
  const float* resz = ORES ? (res + (MODE == 2 ? (long)z * sCb : 0L)) : nullptr;
  const float* Bsel;
  int nb;
  if (n0 < nSplitB) { Bsel = B0; nb = n0; } else { Bsel = B1; nb = n0 - nSplitB; }
  if (MODE == 2) Bsel += (long)z * sBb;

  const int kBeg = (MODE == 1) ? z * kChunk : 0;
  const int kEnd = (MODE == 1) ? kBeg + kChunk : K;

  __shared__ float As[16][68];  // [k][m]
  __shared__ float Bs[16][68];  // [k][n]

  const int tid = threadIdx.x;
  const int tx = tid & 15, ty = tid >> 4;
  const int ar = tid >> 2, ac = (tid & 3) << 2;   // A: row 0..63, k-col {0,4,8,12}
  const int br = tid >> 4, bc = (tid & 15) << 2;  // B: k-row 0..15, col 0..60

  auto loadA = [&](int kt) -> float4 {
    const size_t aoff = (size_t)(m0 + ar) * K + kt + ac;
    if (AFUSE) {
      float4 s = *(const float4*)(Ab + aoff);
#pragma unroll
      for (int p = 1; p < NPART; ++p) {
        const float4 t = *(const float4*)(Ab + (long)p * aPart + aoff);
        s.x += t.x; s.y += t.y; s.z += t.z; s.w += t.w;
      }
      const float4 bz = *(const float4*)(aBias + kt + ac);
      s.x = fmaxf(s.x + bz.x, 0.0f);
      s.y = fmaxf(s.y + bz.y, 0.0f);
      s.z = fmaxf(s.z + bz.z, 0.0f);
      s.w = fmaxf(s.w + bz.w, 0.0f);
      return s;
    }
    return *(const float4*)(Ab + aoff);
  };
  auto loadB = [&](int kt) -> float4 {
    return *(const float4*)(Bsel + (size_t)(kt + br) * ldB + nb + bc);
  };

  float acc[4][4] = {};
  float4 a4 = loadA(kBeg);
  float4 b4 = loadB(kBeg);

  for (int kt = kBeg; kt < kEnd; kt += 16) {
    __syncthreads();
    As[ac + 0][ar] = a4.x;
    As[ac + 1][ar] = a4.y;
    As[ac + 2][ar] = a4.z;
    As[ac + 3][ar] = a4.w;
    *(float4*)&Bs[br][bc] = b4;
    __syncthreads();
    if (kt + 16 < kEnd) {  // prefetch next tile under compute
      a4 = loadA(kt + 16);
      b4 = loadB(kt + 16);
    }
#pragma unroll
    for (int kk = 0; kk < 16; ++kk) {
      const float4 av = *(const float4*)&As[kk][ty << 2];
      const float4 bv = *(const float4*)&Bs[kk][tx << 2];
      const float a[4] = {av.x, av.y, av.z, av.w};
      const float b[4] = {bv.x, bv.y, bv.z, bv.w};
#pragma unroll
      for (int i = 0; i < 4; ++i)
#pragma unroll
        for (int j = 0; j < 4; ++j) acc[i][j] = fmaf(a[i], b[j], acc[i][j]);
    }
  }

#pragma unroll
  for (int i = 0; i < 4; ++i) {
    const int m = m0 + (ty << 2) + i;
#pragma unroll
    for (int j = 0; j < 4; ++j) {
      const int n = n0 + (tx << 2) + j;
      float v = acc[i][j];
      if (OBIAS) v += oBias[n];
      if (ORES) v += resz[(size_t)m * N + n];
      Cb[(size_t)m * N + n] = v;
    }
  }
}

// ---------------------------------------------------------------------------
// Reduce NPART QK partials [1024][256] (cols 0..127=Q, 128..255=K) into:
//   Qd[1024][128]  (dense Q rows)
//   KT[b][h][j]    (K transposed: KT[b*32768 + h*256 + j])
// Grid 1024 (block = row r = b*256+j), 256 threads. Loads fully coalesced;
// the KT scatter-store is paid ONCE here instead of on every scores read.
// ---------------------------------------------------------------------------
__global__ __launch_bounds__(256) void qksum_k(const float* __restrict__ QKp,
                                               long ps,
                                               float* __restrict__ Qd,
                                               float* __restrict__ KT) {
  const int r = blockIdx.x, tid = threadIdx.x;
  const int b = r >> 8, j = r & 255;
  const size_t off = (size_t)r * 256 + tid;
  float v = 0.0f;
#pragma unroll
  for (int p = 0; p < NPART; ++p) v += QKp[(long)p * ps + off];
  if (tid < 128) {
    Qd[(size_t)r * 128 + tid] = v;
  } else {
    KT[(size_t)b * 32768 + (size_t)(tid - 128) * 256 + j] = v;
  }
}

// ---------------------------------------------------------------------------
// Scores + softmax, layers 1-3. Block = (i-tile of 2 rows, b): grid (128, B)
// = 512 blocks (2 blocks/CU). Lane j reads KT[b][h][j] -> coalesced.
// ---------------------------------------------------------------------------
__global__ __launch_bounds__(256) void scores2_k(const float* __restrict__ Qd,
                                                 const float* __restrict__ KT,
                                                 const float* __restrict__ wv,
                                                 float* __restrict__ attn) {
  const int b = blockIdx.y, i0 = blockIdx.x * 2, tid = threadIdx.x;
  __shared__ float qs[2][128], wvs[128], red[4];
  {
    const int rr = tid >> 7, h = tid & 127;
    qs[rr][h] = Qd[(size_t)(b * 256 + i0 + rr) * 128 + h];
  }
  if (tid < 128) wvs[tid] = wv[tid];
  __syncthreads();

  const float* KTb = KT + (size_t)b * 32768 + tid;  // + h*256 indexes below
  float s0 = 0.0f, s1 = 0.0f;
#pragma unroll 4
  for (int h = 0; h < 128; h += 4) {
    const float k0 = KTb[(h + 0) * 256];
    const float k1 = KTb[(h + 1) * 256];
    const float k2 = KTb[(h + 2) * 256];
    const float k3 = KTb[(h + 3) * 256];
    const float w0 = wvs[h], w1 = wvs[h + 1], w2 = wvs[h + 2], w3 = wvs[h + 3];
    s0 += w0 * ftanh(qs[0][h] + k0) + w1 * ftanh(qs[0][h + 1] + k1) +
          w2 * ftanh(qs[0][h + 2] + k2) + w3 * ftanh(qs[0][h + 3] + k3);
    s1 += w0 * ftanh(qs[1][h] + k0) + w1 * ftanh(qs[1][h + 1] + k1) +
          w2 * ftanh(qs[1][h + 2] + k2) + w3 * ftanh(qs[1][h + 3] + k3);
  }
  {
    const float mx = blockMax(s0, red);
    const float e = __expf(s0 - mx);
    const float tot = blockSum(e, red);
    attn[(size_t)(b * 256 + i0) * 256 + tid] = e / tot;
  }
  {
    const float mx = blockMax(s1, red);
    const float e = __expf(s1 - mx);
    const float tot = blockSum(e, red);
    attn[(size_t)(b * 256 + i0 + 1) * 256 + tid] = e / tot;
  }
}

// LN over rows of A -> Y. 1024 blocks.
__global__ __launch_bounds__(256) void ln1_k(const float* __restrict__ A,
                                             float* __restrict__ Y) {
  __shared__ float red[4];
  const int r = blockIdx.x, tid = threadIdx.x;
  const float* a = A + (size_t)r * VEC;
  float v[5];
  float sum = 0.0f;
#pragma unroll
  for (int k = 0; k < 5; ++k) {
    v[k] = a[tid + k * 256];
    sum += v[k];
  }
  sum = blockSum(sum, red);
  const float m = sum * (1.0f / VEC);
  float sq = 0.0f;
#pragma unroll
  for (int k = 0; k < 5; ++k) {
    const float dl = v[k] - m;
    sq += dl * dl;
  }
  sq = blockSum(sq, red);
  const float rstd = rsqrtf(sq * (1.0f / VEC) + 1e-5f);
  float* y = Y + (size_t)r * VEC;
#pragma unroll
  for (int k = 0; k < 5; ++k) y[tid + k * 256] = (v[k] - m) * rstd;
}

// Layer-4 scores: grid (B). q row = Qd[b*256+lp]; lane j reads KT coalesced.
__global__ __launch_bounds__(256) void scores4_k(const float* __restrict__ Qd,
                                                 const float* __restrict__ KT,
                                                 const float* __restrict__ wv4,
                                                 const int* __restrict__ lys,
                                                 float* __restrict__ aw4) {
  const int b = blockIdx.x, tid = threadIdx.x;
  __shared__ float qs[128], wvs[128], red[4];
  const int lp = lys[0];
  if (tid < 128) {
    qs[tid] = Qd[(size_t)(b * 256 + lp) * 128 + tid];
    wvs[tid] = wv4[tid];
  }
  __syncthreads();
  const float* KTb = KT + (size_t)b * 32768 + tid;
  float s = 0.0f;
#pragma unroll 4
  for (int h = 0; h < 128; h += 4) {
    s += wvs[h + 0] * ftanh(qs[h + 0] + KTb[(h + 0) * 256]);
    s += wvs[h + 1] * ftanh(qs[h + 1] + KTb[(h + 1) * 256]);
    s += wvs[h + 2] * ftanh(qs[h + 2] + KTb[(h + 2) * 256]);
    s += wvs[h + 3] * ftanh(qs[h + 3] + KTb[(h + 3) * 256]);
  }
  const float mx = blockMax(s, red);
  const float e = __expf(s - mx);
  const float tot = blockSum(e, red);
  aw4[b * 256 + tid] = e / tot;
}

// pv4_k: grid (B, 5). A4[b][c] = sum_j aw4[b][j]*X3[b,j,c] + X3[b,lp,c].
__global__ __launch_bounds__(256) void pv4_k(const float* __restrict__ aw4,
                                             const float* __restrict__ X3,
                                             const int* __restrict__ lys,
                                             float* __restrict__ A4) {
  const int b = blockIdx.x, c = blockIdx.y * 256 + threadIdx.x;
  __shared__ float aws[256];
  aws[threadIdx.x] = aw4[b * 256 + threadIdx.x];
  __syncthreads();
  const float* Xb = X3 + (size_t)b * SS * VEC;
  float acc = 0.0f;
#pragma unroll 8
  for (int j = 0; j < 256; ++j) acc = fmaf(aws[j], Xb[(size_t)j * VEC + c], acc);
  acc += Xb[(size_t)lys[0] * VEC + c];
  A4[b * VEC + c] = acc;
}

// lnhead_k: grid (B). LN(A4[b]) then 1280->32(relu)->12(relu)->2 head.
__global__ __launch_bounds__(256) void lnhead_k(
    const float* __restrict__ A4,
    const float* __restrict__ hW1, const float* __restrict__ hb1,
    const float* __restrict__ hW2, const float* __restrict__ hb2,
    const float* __restrict__ hW3, const float* __restrict__ hb3,
    float* __restrict__ out) {
  const int b = blockIdx.x, tid = threadIdx.x;
  __shared__ float xrow[1280], partial[256], red[4];
  __shared__ float h1s[32], h2s[12];
  float v[5];
  float sum = 0.0f;
#pragma unroll
  for (int k = 0; k < 5; ++k) {
    v[k] = A4[b * VEC + tid + k * 256];
    sum += v[k];
  }
  sum = blockSum(sum, red);
  const float m = sum * (1.0f / VEC);
  float sq = 0.0f;
#pragma unroll
  for (int k = 0; k < 5; ++k) {
    const float dl = v[k] - m;
    sq += dl * dl;
  }
  sq = blockSum(sq, red);
  const float rstd = rsqrtf(sq * (1.0f / VEC) + 1e-5f);
#pragma unroll
  for (int k = 0; k < 5; ++k) xrow[tid + k * 256] = (v[k] - m) * rstd;
  __syncthreads();
  {
    const int n = tid & 31, sl = tid >> 5;
    float p = 0.0f;
    for (int k = sl * 160; k < sl * 160 + 160; ++k)
      p = fmaf(xrow[k], hW1[(size_t)k * 32 + n], p);
    partial[tid] = p;
  }
  __syncthreads();
  if (tid < 32) {
    float t = 0.0f;
#pragma unroll
    for (int s2 = 0; s2 < 8; ++s2) t += partial[s2 * 32 + tid];
    h1s[tid] = fmaxf(t + hb1[tid], 0.0f);
  }
  __syncthreads();
  if (tid < 12) {
    float t = 0.0f;
#pragma unroll
    for (int k = 0; k < 32; ++k) t = fmaf(h1s[k], hW2[k * 12 + tid], t);
    h2s[tid] = fmaxf(t + hb2[tid], 0.0f);
  }
  __syncthreads();
  if (tid < 2) {
    float t = 0.0f;
#pragma unroll
    for (int k = 0; k < 12; ++k) t = fmaf(h2s[k], hW3[k * 2 + tid], t);
    out[b * 2 + tid] = t + hb3[tid];
  }
}

// ---------------------------------------------------------------------------
extern "C" void kernel_launch(void* const* d_in, const int* in_sizes, int n_in,
                              void* d_out, int out_size, void* d_ws, size_t ws_size,
                              hipStream_t stream) {
  const float* X = (const float*)d_in[0];
  const int* lys = (const int*)d_in[1];
  const float* Wq[4] = {(const float*)d_in[2], (const float*)d_in[5],
                        (const float*)d_in[8], (const float*)d_in[11]};
  const float* Wk[4] = {(const float*)d_in[3], (const float*)d_in[6],
                        (const float*)d_in[9], (const float*)d_in[12]};
  const float* wv[4] = {(const float*)d_in[4], (const float*)d_in[7],
                        (const float*)d_in[10], (const float*)d_in[13]};
  const float* rW1[3] = {(const float*)d_in[14], (const float*)d_in[18],
                         (const float*)d_in[22]};
  const float* rb1[3] = {(const float*)d_in[15], (const float*)d_in[19],
                         (const float*)d_in[23]};
  const float* rW2[3] = {(const float*)d_in[16], (const float*)d_in[20],
                         (const float*)d_in[24]};
  const float* rb2[3] = {(const float*)d_in[17], (const float*)d_in[21],
                         (const float*)d_in[25]};
  const float* hW1 = (const float*)d_in[26];
  const float* hb1 = (const float*)d_in[27];
  const float* hW2 = (const float*)d_in[28];
  const float* hb2 = (const float*)d_in[29];
  const float* hW3 = (const float*)d_in[30];
  const float* hb3 = (const float*)d_in[31];
  float* out = (float*)d_out;

  // Workspace (floats), ~36 MB.
  float* ws = (float*)d_ws;
  const long QK_PS = 262144;                 // QK partial stride (1024*256)
  const long H_PS  = 131072;                 // FC1 partial stride (1024*128)
  float* QKp  = ws;                          // NPART x 262144
  float* Qd   = QKp + (long)NPART * QK_PS;   // 1024*128
  float* KT   = Qd + 131072;                 // 4*128*256
  float* attn = KT + 131072;                 // 1024*256
  float* Yraw = attn + 262144;               // 1024*1280
  float* Yb   = Yraw + 1310720;              // 1024*1280
  float* Hp   = Yb + 1310720;                // NPART x 131072
  float* buf0 = Hp + (long)NPART * H_PS;     // 1024*1280
  float* buf1 = buf0 + 1310720;              // 1024*1280
  float* aw4  = buf1 + 1310720;              // 4*256
  float* A4   = aw4 + 1024;                  // 4*1280

  const int NSPLIT_NONE = 1 << 30;
  const float* P[3] = {X, buf0, buf1};
  float* Q[3] = {buf0, buf1, buf0};

  for (int l = 0; l < 3; ++l) {
    const float* Xin = P[l];
    // QKp[z] = Xin @ [Wq|Wk] over K-slice z (8 slices of 160). 512 blocks.
    gemm_k<1, false, false, false><<<dim3(4, 16, NPART), 256, 0, stream>>>(
        Xin, 0, 0, Wq[l], Wk[l], HID, 0, HID, QKp, QK_PS, nullptr, nullptr,
        nullptr, 256, VEC, 160);
    // Reduce partials -> Qd + KT (transposed K). 1024 blocks.
    qksum_k<<<dim3(MROWS), 256, 0, stream>>>(QKp, QK_PS, Qd, KT);
    // attn = softmax(wv . tanh(q_i + k_j)). 512 blocks.
    scores2_k<<<dim3(128, BB), 256, 0, stream>>>(Qd, KT, wv[l], attn);
    // Yraw = attn @ Xin + Xin (batched, residual fused). 320 blocks.
    gemm_k<2, false, false, true><<<dim3(20, 4, BB), 256, 0, stream>>>(
        attn, (long)SS * SS, 0, Xin, Xin, NSPLIT_NONE, (long)SS * VEC, VEC,
        Yraw, (long)SS * VEC, nullptr, nullptr, Xin, VEC, SS, 0);
    // Yb = LN(Yraw). 1024 blocks.
    ln1_k<<<dim3(MROWS), 256, 0, stream>>>(Yraw, Yb);
    // Hp[z] = Yb @ rW1 over K-slice z (8 slices of 160). 256 blocks.
    gemm_k<1, false, false, false><<<dim3(2, 16, NPART), 256, 0, stream>>>(
        Yb, 0, 0, rW1[l], rW1[l], NSPLIT_NONE, 0, HID, Hp, H_PS, nullptr,
        nullptr, nullptr, HID, VEC, 160);
    // Xout = relu(sum(Hp)+b1) @ rW2 + b2 + Yb. 320 blocks.
    gemm_k<0, true, true, true><<<dim3(20, 16, 1), 256, 0, stream>>>(
        Hp, 0, H_PS, rW2[l], rW2[l], NSPLIT_NONE, 0, VEC, Q[l], 0, rb1[l],
        rb2[l], Yb, VEC, HID, 0);
  }

  const float* X3 = Q[2];  // buf0
  // Layer 4: full QK projection + reduce, then tiny tail kernels.
  gemm_k<1, false, false, false><<<dim3(4, 16, NPART), 256, 0, stream>>>(
      X3, 0, 0, Wq[3], Wk[3], HID, 0, HID, QKp, QK_PS, nullptr, nullptr,
      nullptr, 256, VEC, 160);
  qksum_k<<<dim3(MROWS), 256, 0, stream>>>(QKp, QK_PS, Qd, KT);
  scores4_k<<<dim3(BB), 256, 0, stream>>>(Qd, KT, wv[3], lys, aw4);
  pv4_k<<<dim3(BB, 5), 256, 0, stream>>>(aw4, X3, lys, A4);
  lnhead_k<<<dim3(BB), 256, 0, stream>>>(A4, hW1, hb1, hW2, hb2, hW3, hb3, out);
}